// Round 4
// baseline (96.959 us; speedup 1.0000x reference)
//
#include <hip/hip_runtime.h>
#include <hip/hip_bf16.h>
#include <stdint.h>

#define NB   8
#define NN   2048
#define NE   16384
#define OBS  128
#define HID  256
#define OUTF 1024

using bfrag = __attribute__((ext_vector_type(8))) short;
using ffrag = __attribute__((ext_vector_type(4))) float;

__device__ __forceinline__ short f2bf(float f) {
    __hip_bfloat16 h = __float2bfloat16(f);
    return __builtin_bit_cast(short, h);
}
__device__ __forceinline__ unsigned packbf(float a, float b) {
    return ((unsigned)(unsigned short)f2bf(b) << 16) | (unsigned)(unsigned short)f2bf(a);
}

__device__ __forceinline__ void gload_lds16(const void* g, void* l) {
    __builtin_amdgcn_global_load_lds(
        (const __attribute__((address_space(1))) unsigned int*)g,
        (__attribute__((address_space(3))) unsigned int*)l, 16, 0, 0);
}

// ---------------- weight prep: W0^T, W1^T (f32->bf16) ----------------
__global__ __launch_bounds__(256) void k_prep(const float* __restrict__ W0,
                                              const float* __restrict__ W1,
                                              short* __restrict__ W0t,
                                              short* __restrict__ W1t) {
    int idx = blockIdx.x * 256 + threadIdx.x;
    if (idx < HID * OUTF) {  // W1t [OUTF][HID]
        int n = idx / HID, k = idx - n * HID;
        W1t[idx] = f2bf(W1[k * OUTF + n]);
    }
    if (idx < OBS * HID) {   // W0t [HID][OBS]
        int n = idx / OBS, k = idx - n * OBS;
        W0t[idx] = f2bf(W0[k * HID + n]);
    }
}

// ---------------- fused graph setup: one block per graph ----------------
// counts (LDS atomics) -> block scan -> offsets/dinv -> CSR fill (+ norms)
__global__ __launch_bounds__(1024) void k_graph(const int* __restrict__ edges,
                                                int* __restrict__ offsets,
                                                float* __restrict__ dinv,
                                                int* __restrict__ csr,
                                                float* __restrict__ wcsr) {
    const int b = blockIdx.x, t = threadIdx.x;
    __shared__ int   cnt[NN];
    __shared__ int   cur[NN];
    __shared__ float dv[NN];
    __shared__ int   sc[1024];
    cnt[t] = 0;
    cnt[t + 1024] = 0;
    __syncthreads();
    const int* ed   = edges + (size_t)b * 2 * NE;
    const int* dsts = ed + NE;
    for (int e = t; e < NE; e += 1024)
        atomicAdd(&cnt[dsts[e]], 1);
    __syncthreads();
    const int c0 = cnt[2 * t], c1 = cnt[2 * t + 1];
    const int s = c0 + c1;
    sc[t] = s;
    const float d0 = rsqrtf((float)(c0 + 1));
    const float d1 = rsqrtf((float)(c1 + 1));
    dv[2 * t] = d0;
    dv[2 * t + 1] = d1;
    __syncthreads();
    for (int d = 1; d < 1024; d <<= 1) {
        int v = (t >= d) ? sc[t - d] : 0;
        __syncthreads();
        if (t >= d) sc[t] += v;
        __syncthreads();
    }
    const int excl = sc[t] - s;
    cur[2 * t] = excl;
    cur[2 * t + 1] = excl + c0;
    offsets[b * (NN + 1) + 2 * t] = excl;
    offsets[b * (NN + 1) + 2 * t + 1] = excl + c0;
    dinv[b * NN + 2 * t] = d0;
    dinv[b * NN + 2 * t + 1] = d1;
    if (t == 0) offsets[b * (NN + 1) + NN] = NE;
    __syncthreads();
    for (int e = t; e < NE; e += 1024) {
        int srcv = ed[e];
        int dstv = dsts[e];
        int pos = atomicAdd(&cur[dstv], 1);
        csr[(size_t)b * NE + pos] = srcv;
        wcsr[(size_t)b * NE + pos] = dv[dstv] * dv[srcv];
    }
}

// ---------------- pre-GEMM aggregation (S x) ----------------
// z0 = S . nodes  (f32 in -> bf16 out, F=128). 64 thr x 2 elems.
__global__ __launch_bounds__(64) void k_agg0(const float* __restrict__ nodes,
                                             const float* __restrict__ dinv,
                                             const int* __restrict__ csr,
                                             const float* __restrict__ wcsr,
                                             const int* __restrict__ offs,
                                             unsigned* __restrict__ z0) {
    const int i = blockIdx.x, b = blockIdx.y, t = threadIdx.x;
    const float* xb = nodes + (size_t)b * NN * OBS;
    const float di = dinv[b * NN + i];
    const int o0 = offs[b * (NN + 1) + i], o1 = offs[b * (NN + 1) + i + 1];
    float2 v = *(const float2*)&xb[(size_t)i * OBS + t * 2];
    float ax = di * di * v.x, ay = di * di * v.y;
    const int* cs = csr + (size_t)b * NE;
    const float* wc = wcsr + (size_t)b * NE;
    for (int e = o0; e < o1; ++e) {
        int s = cs[e];
        float w = wc[e];
        float2 u = *(const float2*)&xb[(size_t)s * OBS + t * 2];
        ax = fmaf(w, u.x, ax);
        ay = fmaf(w, u.y, ay);
    }
    z0[(((size_t)b * NN + i) * OBS + t * 2) >> 1] = packbf(ax, ay);
}

// z1 = S . x1  (bf16 in -> bf16 out, F=256). 64 thr x 4 elems.
__global__ __launch_bounds__(64) void k_agg1(const short* __restrict__ x1,
                                             const float* __restrict__ dinv,
                                             const int* __restrict__ csr,
                                             const float* __restrict__ wcsr,
                                             const int* __restrict__ offs,
                                             unsigned* __restrict__ z1) {
    const int i = blockIdx.x, b = blockIdx.y, t = threadIdx.x;
    const short* xb = x1 + (size_t)b * NN * HID;
    const float di = dinv[b * NN + i];
    const int o0 = offs[b * (NN + 1) + i], o1 = offs[b * (NN + 1) + i + 1];
    uint2 raw = *(const uint2*)&xb[(size_t)i * HID + t * 4];
    float di2 = di * di;
    float a0 = di2 * __uint_as_float(raw.x << 16);
    float a1 = di2 * __uint_as_float(raw.x & 0xffff0000u);
    float a2 = di2 * __uint_as_float(raw.y << 16);
    float a3 = di2 * __uint_as_float(raw.y & 0xffff0000u);
    const int* cs = csr + (size_t)b * NE;
    const float* wc = wcsr + (size_t)b * NE;
    for (int e = o0; e < o1; ++e) {
        int s = cs[e];
        float w = wc[e];
        uint2 u = *(const uint2*)&xb[(size_t)s * HID + t * 4];
        a0 = fmaf(w, __uint_as_float(u.x << 16), a0);
        a1 = fmaf(w, __uint_as_float(u.x & 0xffff0000u), a1);
        a2 = fmaf(w, __uint_as_float(u.y << 16), a2);
        a3 = fmaf(w, __uint_as_float(u.y & 0xffff0000u), a3);
    }
    uint2 o;
    o.x = packbf(a0, a1);
    o.y = packbf(a2, a3);
    *(uint2*)&z1[(((size_t)b * NN + i) * HID + t * 4) >> 1] = o;
}

// ---------------- bf16 MFMA GEMM: C = relu(A @ Bt^T + bias) ----------------
// A [M][K] bf16 row-major, Bt [N][K] bf16 (pre-transposed weights).
// 128x128 tile, BK=64, 4 waves (2x2 of 64x64), double-buffered LDS,
// global_load_lds width-16 staging (m97 structure).
template <int K, int N, bool OUT_BF16>
__global__ __launch_bounds__(256, 2) void gemm_mfma(const short* __restrict__ A,
                                                    const short* __restrict__ Bt,
                                                    const float* __restrict__ bias,
                                                    void* __restrict__ Cv) {
    __shared__ short lds[2][2][128 * 64];  // [buf][A|B][row*64 + k] bf16
    const int tid = threadIdx.x;
    const int lane = tid & 63;
    const int wid = tid >> 6;
    const int wr = wid >> 1, wc = wid & 1;
    const int lrow = lane & 15, lk = (lane >> 4) * 8;
    const int row0 = blockIdx.x * 128, col0 = blockIdx.y * 128;
    const short* gA = A + (size_t)row0 * K;
    const short* gB = Bt + (size_t)col0 * K;

    auto stage = [&](int buf, int kt) {
#pragma unroll
        for (int c = 0; c < 4; ++c) {
            int off = c * 4096 + tid * 16;  // byte offset within 16KB tile
            int row = off >> 7, kb = off & 127;
            gload_lds16(gA + (size_t)row * K + kt + (kb >> 1), (char*)&lds[buf][0][0] + off);
            gload_lds16(gB + (size_t)row * K + kt + (kb >> 1), (char*)&lds[buf][1][0] + off);
        }
    };

    ffrag acc[4][4] = {};
    stage(0, 0);
    __syncthreads();
    const int NT = K / 64;
    int cur = 0;
    for (int kt = 0; kt < NT; ++kt) {
        if (kt + 1 < NT) stage(cur ^ 1, (kt + 1) * 64);
        const short* As = &lds[cur][0][0];
        const short* Bs = &lds[cur][1][0];
#pragma unroll
        for (int kk = 0; kk < 2; ++kk) {
            bfrag a[4], b[4];
#pragma unroll
            for (int m = 0; m < 4; ++m)
                a[m] = *(const bfrag*)&As[(wr * 64 + m * 16 + lrow) * 64 + kk * 32 + lk];
#pragma unroll
            for (int n = 0; n < 4; ++n)
                b[n] = *(const bfrag*)&Bs[(wc * 64 + n * 16 + lrow) * 64 + kk * 32 + lk];
#pragma unroll
            for (int m = 0; m < 4; ++m)
#pragma unroll
                for (int n = 0; n < 4; ++n)
                    acc[m][n] = __builtin_amdgcn_mfma_f32_16x16x32_bf16(a[m], b[n], acc[m][n], 0, 0, 0);
        }
        __syncthreads();
        cur ^= 1;
    }

    // epilogue: bias + relu, store
    const int orow = row0 + wr * 64 + (lane >> 4) * 4;
    const int ocol = col0 + wc * 64 + lrow;
#pragma unroll
    for (int n = 0; n < 4; ++n) {
        float bv = bias[ocol + n * 16];
#pragma unroll
        for (int m = 0; m < 4; ++m) {
#pragma unroll
            for (int r = 0; r < 4; ++r) {
                float v = fmaxf(acc[m][n][r] + bv, 0.f);
                size_t idx = (size_t)(orow + m * 16 + r) * N + (ocol + n * 16);
                if constexpr (OUT_BF16)
                    ((short*)Cv)[idx] = f2bf(v);
                else
                    ((float*)Cv)[idx] = v;
            }
        }
    }
}

extern "C" void kernel_launch(void* const* d_in, const int* in_sizes, int n_in,
                              void* d_out, int out_size, void* d_ws, size_t ws_size,
                              hipStream_t stream) {
    const float* nodes = (const float*)d_in[0];
    const int*   edges = (const int*)d_in[1];
    const float* W0    = (const float*)d_in[2];
    const float* b0    = (const float*)d_in[3];
    const float* W1    = (const float*)d_in[4];
    const float* b1    = (const float*)d_in[5];
    float* out = (float*)d_out;

    char* ws = (char*)d_ws;
    size_t off = 0;
    auto alloc = [&](size_t bytes) -> char* {
        char* p = ws + off;
        off = (off + bytes + 255) & ~(size_t)255;
        return p;
    };
    float* dinv   = (float*)alloc((size_t)NB * NN * 4);
    int*   offs   = (int*)alloc((size_t)NB * (NN + 1) * 4);
    int*   csr    = (int*)alloc((size_t)NB * NE * 4);
    float* wcsr   = (float*)alloc((size_t)NB * NE * 4);
    short* W0t    = (short*)alloc((size_t)HID * OBS * 2);
    short* W1t    = (short*)alloc((size_t)OUTF * HID * 2);
    short* z0     = (short*)alloc((size_t)NB * NN * OBS * 2);   // 4 MB
    short* x1     = (short*)alloc((size_t)NB * NN * HID * 2);   // 8 MB
    short* z1     = (short*)alloc((size_t)NB * NN * HID * 2);   // 8 MB

    // 1: weight transposes (bf16)
    k_prep<<<(HID * OUTF + 255) / 256, 256, 0, stream>>>(W0, W1, W0t, W1t);
    // 2: fused graph setup (counts -> scan -> CSR fill, all LDS-side)
    k_graph<<<NB, 1024, 0, stream>>>(edges, offs, dinv, csr, wcsr);

    // 3-4: Layer 1: z0 = S.nodes ; x1 = relu(z0 @ W0 + b0)   [bf16]
    k_agg0<<<dim3(NN, NB), 64, 0, stream>>>(nodes, dinv, csr, wcsr, offs, (unsigned*)z0);
    gemm_mfma<OBS, HID, true><<<dim3(NB * NN / 128, HID / 128), 256, 0, stream>>>(z0, W0t, b0, x1);

    // 5-6: Layer 2: z1 = S.x1 ; out = relu(z1 @ W1 + b1)     [f32 out]
    k_agg1<<<dim3(NN, NB), 64, 0, stream>>>(x1, dinv, csr, wcsr, offs, (unsigned*)z1);
    gemm_mfma<HID, OUTF, false><<<dim3(NB * NN / 128, OUTF / 128), 256, 0, stream>>>(z1, W1t, b1, out);
}

// Round 5
// 80.958 us; speedup vs baseline: 1.1977x; 1.1977x over previous
//
#include <hip/hip_runtime.h>
#include <hip/hip_bf16.h>
#include <stdint.h>

#define NB   8
#define NN   2048
#define NE   16384
#define OBS  128
#define HID  256
#define OUTF 1024

using bfrag = __attribute__((ext_vector_type(8))) short;
using ffrag = __attribute__((ext_vector_type(4))) float;

__device__ __forceinline__ short f2bf(float f) {
    __hip_bfloat16 h = __float2bfloat16(f);
    return __builtin_bit_cast(short, h);
}
__device__ __forceinline__ unsigned packbf(float a, float b) {
    return ((unsigned)(unsigned short)f2bf(b) << 16) | (unsigned)(unsigned short)f2bf(a);
}

__device__ __forceinline__ void gload_lds16(const void* g, void* l) {
    __builtin_amdgcn_global_load_lds(
        (const __attribute__((address_space(1))) unsigned int*)g,
        (__attribute__((address_space(3))) unsigned int*)l, 16, 0, 0);
}

// ---------------- prep: W0^T, W1^T (f32->bf16) + zero counts ----------------
__global__ __launch_bounds__(256) void k_prep(const float* __restrict__ W0,
                                              const float* __restrict__ W1,
                                              short* __restrict__ W0t,
                                              short* __restrict__ W1t,
                                              int* __restrict__ counts) {
    int idx = blockIdx.x * 256 + threadIdx.x;
    if (idx < HID * OUTF) {  // W1t [OUTF][HID]
        int n = idx / HID, k = idx - n * HID;
        W1t[idx] = f2bf(W1[k * OUTF + n]);
    }
    if (idx < OBS * HID) {   // W0t [HID][OBS]
        int n = idx / OBS, k = idx - n * OBS;
        W0t[idx] = f2bf(W0[k * HID + n]);
    }
    if (idx < NB * NN) counts[idx] = 0;
}

// ---------------- graph setup (split, device-wide atomics) ----------------
__global__ __launch_bounds__(256) void k_count(const int* __restrict__ edges,
                                               int* __restrict__ counts) {
    int idx = blockIdx.x * 256 + threadIdx.x;
    if (idx >= NB * NE) return;
    int b = idx / NE, e = idx - b * NE;
    int dst = edges[(size_t)b * 2 * NE + NE + e];
    atomicAdd(&counts[b * NN + dst], 1);
}

__global__ __launch_bounds__(256) void k_scan(const int* __restrict__ counts,
                                              int* __restrict__ offsets,
                                              int* __restrict__ cursor,
                                              float* __restrict__ dinv) {
    const int b = blockIdx.x, t = threadIdx.x;
    const int base = b * NN + t * 8;
    int local[8];
    int s = 0;
#pragma unroll
    for (int j = 0; j < 8; ++j) {
        int c = counts[base + j];
        local[j] = s;
        s += c;
        dinv[base + j] = rsqrtf((float)(c + 1));
    }
    __shared__ int sc[256];
    sc[t] = s;
    __syncthreads();
    for (int d = 1; d < 256; d <<= 1) {
        int v = (t >= d) ? sc[t - d] : 0;
        __syncthreads();
        if (t >= d) sc[t] += v;
        __syncthreads();
    }
    int excl = sc[t] - s;
#pragma unroll
    for (int j = 0; j < 8; ++j) {
        int val = excl + local[j];
        offsets[b * (NN + 1) + t * 8 + j] = val;
        cursor[base + j] = val;
    }
    if (t == 0) offsets[b * (NN + 1) + NN] = NE;
}

// CSR fill + per-edge precomputed norm = dinv[dst]*dinv[src]
__global__ __launch_bounds__(256) void k_fill(const int* __restrict__ edges,
                                              const float* __restrict__ dinv,
                                              int* __restrict__ cursor,
                                              int* __restrict__ csr,
                                              float* __restrict__ wcsr) {
    int idx = blockIdx.x * 256 + threadIdx.x;
    if (idx >= NB * NE) return;
    int b = idx / NE, e = idx - b * NE;
    int src = edges[(size_t)b * 2 * NE + e];
    int dst = edges[(size_t)b * 2 * NE + NE + e];
    int pos = atomicAdd(&cursor[b * NN + dst], 1);
    csr[(size_t)b * NE + pos] = src;
    wcsr[(size_t)b * NE + pos] = dinv[b * NN + dst] * dinv[b * NN + src];
}

// ---------------- pre-GEMM aggregation (S x) ----------------
// z0 = S . nodes  (f32 in -> bf16 out, F=128). 64 thr x 2 elems.
__global__ __launch_bounds__(64) void k_agg0(const float* __restrict__ nodes,
                                             const float* __restrict__ dinv,
                                             const int* __restrict__ csr,
                                             const float* __restrict__ wcsr,
                                             const int* __restrict__ offs,
                                             unsigned* __restrict__ z0) {
    const int i = blockIdx.x, b = blockIdx.y, t = threadIdx.x;
    const float* xb = nodes + (size_t)b * NN * OBS;
    const float di = dinv[b * NN + i];
    const int o0 = offs[b * (NN + 1) + i], o1 = offs[b * (NN + 1) + i + 1];
    float2 v = *(const float2*)&xb[(size_t)i * OBS + t * 2];
    float ax = di * di * v.x, ay = di * di * v.y;
    const int* cs = csr + (size_t)b * NE;
    const float* wc = wcsr + (size_t)b * NE;
    for (int e = o0; e < o1; ++e) {
        int s = cs[e];
        float w = wc[e];
        float2 u = *(const float2*)&xb[(size_t)s * OBS + t * 2];
        ax = fmaf(w, u.x, ax);
        ay = fmaf(w, u.y, ay);
    }
    z0[(((size_t)b * NN + i) * OBS + t * 2) >> 1] = packbf(ax, ay);
}

// z1 = S . x1  (bf16 in -> bf16 out, F=256). 64 thr x 4 elems.
__global__ __launch_bounds__(64) void k_agg1(const short* __restrict__ x1,
                                             const float* __restrict__ dinv,
                                             const int* __restrict__ csr,
                                             const float* __restrict__ wcsr,
                                             const int* __restrict__ offs,
                                             unsigned* __restrict__ z1) {
    const int i = blockIdx.x, b = blockIdx.y, t = threadIdx.x;
    const short* xb = x1 + (size_t)b * NN * HID;
    const float di = dinv[b * NN + i];
    const int o0 = offs[b * (NN + 1) + i], o1 = offs[b * (NN + 1) + i + 1];
    uint2 raw = *(const uint2*)&xb[(size_t)i * HID + t * 4];
    float di2 = di * di;
    float a0 = di2 * __uint_as_float(raw.x << 16);
    float a1 = di2 * __uint_as_float(raw.x & 0xffff0000u);
    float a2 = di2 * __uint_as_float(raw.y << 16);
    float a3 = di2 * __uint_as_float(raw.y & 0xffff0000u);
    const int* cs = csr + (size_t)b * NE;
    const float* wc = wcsr + (size_t)b * NE;
    for (int e = o0; e < o1; ++e) {
        int s = cs[e];
        float w = wc[e];
        uint2 u = *(const uint2*)&xb[(size_t)s * HID + t * 4];
        a0 = fmaf(w, __uint_as_float(u.x << 16), a0);
        a1 = fmaf(w, __uint_as_float(u.x & 0xffff0000u), a1);
        a2 = fmaf(w, __uint_as_float(u.y << 16), a2);
        a3 = fmaf(w, __uint_as_float(u.y & 0xffff0000u), a3);
    }
    uint2 o;
    o.x = packbf(a0, a1);
    o.y = packbf(a2, a3);
    *(uint2*)&z1[(((size_t)b * NN + i) * HID + t * 4) >> 1] = o;
}

// ---------------- bf16 MFMA GEMM: C = relu(A @ Bt^T + bias) ----------------
// A [M][K] bf16 row-major, Bt [N][K] bf16 (pre-transposed weights).
// 128x128 tile, BK=64, 4 waves (2x2 of 64x64), double-buffered LDS,
// global_load_lds width-16 staging (m97 structure).
// 1D grid with XCD-locality remap: all NC col-tiles of a row-panel map to the
// same XCD in consecutive dispatch rounds -> A-panel L2-resident, read once.
template <int K, int N, bool OUT_BF16>
__global__ __launch_bounds__(256, 2) void gemm_mfma(const short* __restrict__ A,
                                                    const short* __restrict__ Bt,
                                                    const float* __restrict__ bias,
                                                    void* __restrict__ Cv) {
    __shared__ short lds[2][2][128 * 64];  // [buf][A|B][row*64 + k] bf16
    constexpr int NC = N / 128;
    const int h = blockIdx.x;
    const int rtile = (h & 7) + 8 * (h / (8 * NC));  // row-panel (XCD-grouped)
    const int ctile = (h >> 3) % NC;                 // col-panel
    const int tid = threadIdx.x;
    const int lane = tid & 63;
    const int wid = tid >> 6;
    const int wr = wid >> 1, wc = wid & 1;
    const int lrow = lane & 15, lk = (lane >> 4) * 8;
    const int row0 = rtile * 128, col0 = ctile * 128;
    const short* gA = A + (size_t)row0 * K;
    const short* gB = Bt + (size_t)col0 * K;

    auto stage = [&](int buf, int kt) {
#pragma unroll
        for (int c = 0; c < 4; ++c) {
            int off = c * 4096 + tid * 16;  // byte offset within 16KB tile
            int row = off >> 7, kb = off & 127;
            gload_lds16(gA + (size_t)row * K + kt + (kb >> 1), (char*)&lds[buf][0][0] + off);
            gload_lds16(gB + (size_t)row * K + kt + (kb >> 1), (char*)&lds[buf][1][0] + off);
        }
    };

    ffrag acc[4][4] = {};
    stage(0, 0);
    __syncthreads();
    const int NT = K / 64;
    int cur = 0;
    for (int kt = 0; kt < NT; ++kt) {
        if (kt + 1 < NT) stage(cur ^ 1, (kt + 1) * 64);
        const short* As = &lds[cur][0][0];
        const short* Bs = &lds[cur][1][0];
#pragma unroll
        for (int kk = 0; kk < 2; ++kk) {
            bfrag a[4], b[4];
#pragma unroll
            for (int m = 0; m < 4; ++m)
                a[m] = *(const bfrag*)&As[(wr * 64 + m * 16 + lrow) * 64 + kk * 32 + lk];
#pragma unroll
            for (int n = 0; n < 4; ++n)
                b[n] = *(const bfrag*)&Bs[(wc * 64 + n * 16 + lrow) * 64 + kk * 32 + lk];
#pragma unroll
            for (int m = 0; m < 4; ++m)
#pragma unroll
                for (int n = 0; n < 4; ++n)
                    acc[m][n] = __builtin_amdgcn_mfma_f32_16x16x32_bf16(a[m], b[n], acc[m][n], 0, 0, 0);
        }
        __syncthreads();
        cur ^= 1;
    }

    // epilogue: bias + relu, store
    const int orow = row0 + wr * 64 + (lane >> 4) * 4;
    const int ocol = col0 + wc * 64 + lrow;
#pragma unroll
    for (int n = 0; n < 4; ++n) {
        float bv = bias[ocol + n * 16];
#pragma unroll
        for (int m = 0; m < 4; ++m) {
#pragma unroll
            for (int r = 0; r < 4; ++r) {
                float v = fmaxf(acc[m][n][r] + bv, 0.f);
                size_t idx = (size_t)(orow + m * 16 + r) * N + (ocol + n * 16);
                if constexpr (OUT_BF16)
                    ((short*)Cv)[idx] = f2bf(v);
                else
                    ((float*)Cv)[idx] = v;
            }
        }
    }
}

extern "C" void kernel_launch(void* const* d_in, const int* in_sizes, int n_in,
                              void* d_out, int out_size, void* d_ws, size_t ws_size,
                              hipStream_t stream) {
    const float* nodes = (const float*)d_in[0];
    const int*   edges = (const int*)d_in[1];
    const float* W0    = (const float*)d_in[2];
    const float* b0    = (const float*)d_in[3];
    const float* W1    = (const float*)d_in[4];
    const float* b1    = (const float*)d_in[5];
    float* out = (float*)d_out;

    char* ws = (char*)d_ws;
    size_t off = 0;
    auto alloc = [&](size_t bytes) -> char* {
        char* p = ws + off;
        off = (off + bytes + 255) & ~(size_t)255;
        return p;
    };
    float* dinv   = (float*)alloc((size_t)NB * NN * 4);
    int*   counts = (int*)alloc((size_t)NB * NN * 4);
    int*   offs   = (int*)alloc((size_t)NB * (NN + 1) * 4);
    int*   cursor = (int*)alloc((size_t)NB * NN * 4);
    int*   csr    = (int*)alloc((size_t)NB * NE * 4);
    float* wcsr   = (float*)alloc((size_t)NB * NE * 4);
    short* W0t    = (short*)alloc((size_t)HID * OBS * 2);
    short* W1t    = (short*)alloc((size_t)OUTF * HID * 2);
    short* z0     = (short*)alloc((size_t)NB * NN * OBS * 2);   // 4 MB
    short* x1     = (short*)alloc((size_t)NB * NN * HID * 2);   // 8 MB
    short* z1     = (short*)alloc((size_t)NB * NN * HID * 2);   // 8 MB

    // 1: weight transposes + zero counts
    k_prep<<<(HID * OUTF + 255) / 256, 256, 0, stream>>>(W0, W1, W0t, W1t, counts);
    // 2-4: degree count -> scan (offsets, dinv) -> CSR fill (+ per-edge norm)
    k_count<<<(NB * NE + 255) / 256, 256, 0, stream>>>(edges, counts);
    k_scan<<<NB, 256, 0, stream>>>(counts, offs, cursor, dinv);
    k_fill<<<(NB * NE + 255) / 256, 256, 0, stream>>>(edges, dinv, cursor, csr, wcsr);

    // 5-6: Layer 1: z0 = S.nodes ; x1 = relu(z0 @ W0 + b0)   [bf16]
    k_agg0<<<dim3(NN, NB), 64, 0, stream>>>(nodes, dinv, csr, wcsr, offs, (unsigned*)z0);
    gemm_mfma<OBS, HID, true><<<(NB * NN / 128) * (HID / 128), 256, 0, stream>>>(z0, W0t, b0, x1);

    // 7-8: Layer 2: z1 = S.x1 ; out = relu(z1 @ W1 + b1)     [f32 out]
    k_agg1<<<dim3(NN, NB), 64, 0, stream>>>(x1, dinv, csr, wcsr, offs, (unsigned*)z1);
    gemm_mfma<HID, OUTF, false><<<(NB * NN / 128) * (OUTF / 128), 256, 0, stream>>>(z1, W1t, b1, out);
}

// Round 6
// 73.054 us; speedup vs baseline: 1.3272x; 1.1082x over previous
//
#include <hip/hip_runtime.h>
#include <hip/hip_bf16.h>
#include <stdint.h>

#define NB   8
#define NN   2048
#define NE   16384
#define OBS  128
#define HID  256
#define OUTF 1024
#define BCAP 64   // per-node bucket capacity (max in-degree; mean 8, sigma 2.8)

using bfrag = __attribute__((ext_vector_type(8))) short;
using ffrag = __attribute__((ext_vector_type(4))) float;

__device__ __forceinline__ short f2bf(float f) {
    __hip_bfloat16 h = __float2bfloat16(f);
    return __builtin_bit_cast(short, h);
}
__device__ __forceinline__ unsigned packbf(float a, float b) {
    return ((unsigned)(unsigned short)f2bf(b) << 16) | (unsigned)(unsigned short)f2bf(a);
}

__device__ __forceinline__ void gload_lds16(const void* g, void* l) {
    __builtin_amdgcn_global_load_lds(
        (const __attribute__((address_space(1))) unsigned int*)g,
        (__attribute__((address_space(3))) unsigned int*)l, 16, 0, 0);
}

// ---------------- prep: W0^T, W1^T (f32->bf16) + zero cnt ----------------
__global__ __launch_bounds__(256) void k_prep(const float* __restrict__ W0,
                                              const float* __restrict__ W1,
                                              short* __restrict__ W0t,
                                              short* __restrict__ W1t,
                                              int* __restrict__ cnt) {
    int idx = blockIdx.x * 256 + threadIdx.x;
    if (idx < HID * OUTF) {  // W1t [OUTF][HID]
        int n = idx / HID, k = idx - n * HID;
        W1t[idx] = f2bf(W1[k * OUTF + n]);
    }
    if (idx < OBS * HID) {   // W0t [HID][OBS]
        int n = idx / OBS, k = idx - n * OBS;
        W0t[idx] = f2bf(W0[k * HID + n]);
    }
    if (idx < NB * NN) cnt[idx] = 0;
}

// ---------------- bucket scatter: bucket[b][dst][cnt++] = src ----------------
__global__ __launch_bounds__(256) void k_bucket(const int* __restrict__ edges,
                                                int* __restrict__ cnt,
                                                int* __restrict__ bucket) {
    int idx = blockIdx.x * 256 + threadIdx.x;
    if (idx >= NB * NE) return;
    int b = idx / NE, e = idx - b * NE;
    int src = edges[(size_t)b * 2 * NE + e];
    int dst = edges[(size_t)b * 2 * NE + NE + e];
    int pos = atomicAdd(&cnt[b * NN + dst], 1);
    if (pos < BCAP) bucket[((size_t)b * NN + dst) * BCAP + pos] = src;
}

// ---------------- pre-GEMM aggregation z = S.x ----------------
// 256 thr = 4 waves, 1 wave per dst node. Lane t pre-gathers (s_t, dv_t) in one
// parallel latency round; edge loop gets (s,w) via __shfl (register broadcast).

// z0 = S . nodes  (f32 in -> bf16 out, F=128; 2 f32/lane)
__global__ __launch_bounds__(256) void k_agg0(const float* __restrict__ nodes,
                                              const int* __restrict__ cnt,
                                              const int* __restrict__ bucket,
                                              unsigned* __restrict__ z0) {
    const int b = blockIdx.y, t = threadIdx.x;
    const int i = blockIdx.x * 4 + (t >> 6);
    const int l = t & 63;
    const int* cb = cnt + b * NN;
    const int deg = cb[i];
    const float di = rsqrtf((float)(deg + 1));
    int s_t = 0;
    float dv_t = 0.f;
    if (l < deg) {
        s_t = bucket[((size_t)b * NN + i) * BCAP + l];
        dv_t = rsqrtf((float)(cb[s_t] + 1));
    }
    const float* xb = nodes + (size_t)b * NN * OBS;
    float2 v = *(const float2*)&xb[(size_t)i * OBS + l * 2];
    float ax = di * di * v.x, ay = di * di * v.y;
    for (int e = 0; e < deg; ++e) {
        int s = __shfl(s_t, e);
        float w = di * __shfl(dv_t, e);
        float2 u = *(const float2*)&xb[(size_t)s * OBS + l * 2];
        ax = fmaf(w, u.x, ax);
        ay = fmaf(w, u.y, ay);
    }
    z0[(((size_t)b * NN + i) * OBS + l * 2) >> 1] = packbf(ax, ay);
}

// z1 = S . x1  (bf16 in -> bf16 out, F=256; 4 bf16/lane)
__global__ __launch_bounds__(256) void k_agg1(const short* __restrict__ x1,
                                              const int* __restrict__ cnt,
                                              const int* __restrict__ bucket,
                                              unsigned* __restrict__ z1) {
    const int b = blockIdx.y, t = threadIdx.x;
    const int i = blockIdx.x * 4 + (t >> 6);
    const int l = t & 63;
    const int* cb = cnt + b * NN;
    const int deg = cb[i];
    const float di = rsqrtf((float)(deg + 1));
    int s_t = 0;
    float dv_t = 0.f;
    if (l < deg) {
        s_t = bucket[((size_t)b * NN + i) * BCAP + l];
        dv_t = rsqrtf((float)(cb[s_t] + 1));
    }
    const short* xb = x1 + (size_t)b * NN * HID;
    uint2 raw = *(const uint2*)&xb[(size_t)i * HID + l * 4];
    const float di2 = di * di;
    float a0 = di2 * __uint_as_float(raw.x << 16);
    float a1 = di2 * __uint_as_float(raw.x & 0xffff0000u);
    float a2 = di2 * __uint_as_float(raw.y << 16);
    float a3 = di2 * __uint_as_float(raw.y & 0xffff0000u);
    for (int e = 0; e < deg; ++e) {
        int s = __shfl(s_t, e);
        float w = di * __shfl(dv_t, e);
        uint2 u = *(const uint2*)&xb[(size_t)s * HID + l * 4];
        a0 = fmaf(w, __uint_as_float(u.x << 16), a0);
        a1 = fmaf(w, __uint_as_float(u.x & 0xffff0000u), a1);
        a2 = fmaf(w, __uint_as_float(u.y << 16), a2);
        a3 = fmaf(w, __uint_as_float(u.y & 0xffff0000u), a3);
    }
    uint2 o;
    o.x = packbf(a0, a1);
    o.y = packbf(a2, a3);
    *(uint2*)&z1[(((size_t)b * NN + i) * HID + l * 4) >> 1] = o;
}

// ---------------- bf16 MFMA GEMM: C = relu(A @ Bt^T + bias) ----------------
// A [M][K] bf16 row-major, Bt [N][K] bf16 (pre-transposed weights).
// 128x128 tile, BK=64, 4 waves (2x2 of 64x64), double-buffered LDS,
// global_load_lds width-16 staging (m97 structure). XCD-grouped 1D grid remap.
template <int K, int N, bool OUT_BF16>
__global__ __launch_bounds__(256, 2) void gemm_mfma(const short* __restrict__ A,
                                                    const short* __restrict__ Bt,
                                                    const float* __restrict__ bias,
                                                    void* __restrict__ Cv) {
    __shared__ short lds[2][2][128 * 64];  // [buf][A|B][row*64 + k] bf16
    constexpr int NC = N / 128;
    const int h = blockIdx.x;
    const int rtile = (h & 7) + 8 * (h / (8 * NC));  // row-panel (XCD-grouped)
    const int ctile = (h >> 3) % NC;                 // col-panel
    const int tid = threadIdx.x;
    const int lane = tid & 63;
    const int wid = tid >> 6;
    const int wr = wid >> 1, wc = wid & 1;
    const int lrow = lane & 15, lk = (lane >> 4) * 8;
    const int row0 = rtile * 128, col0 = ctile * 128;
    const short* gA = A + (size_t)row0 * K;
    const short* gB = Bt + (size_t)col0 * K;

    auto stage = [&](int buf, int kt) {
#pragma unroll
        for (int c = 0; c < 4; ++c) {
            int off = c * 4096 + tid * 16;  // byte offset within 16KB tile
            int row = off >> 7, kb = off & 127;
            gload_lds16(gA + (size_t)row * K + kt + (kb >> 1), (char*)&lds[buf][0][0] + off);
            gload_lds16(gB + (size_t)row * K + kt + (kb >> 1), (char*)&lds[buf][1][0] + off);
        }
    };

    ffrag acc[4][4] = {};
    stage(0, 0);
    __syncthreads();
    const int NT = K / 64;
    int cur = 0;
    for (int kt = 0; kt < NT; ++kt) {
        if (kt + 1 < NT) stage(cur ^ 1, (kt + 1) * 64);
        const short* As = &lds[cur][0][0];
        const short* Bs = &lds[cur][1][0];
#pragma unroll
        for (int kk = 0; kk < 2; ++kk) {
            bfrag a[4], b[4];
#pragma unroll
            for (int m = 0; m < 4; ++m)
                a[m] = *(const bfrag*)&As[(wr * 64 + m * 16 + lrow) * 64 + kk * 32 + lk];
#pragma unroll
            for (int n = 0; n < 4; ++n)
                b[n] = *(const bfrag*)&Bs[(wc * 64 + n * 16 + lrow) * 64 + kk * 32 + lk];
#pragma unroll
            for (int m = 0; m < 4; ++m)
#pragma unroll
                for (int n = 0; n < 4; ++n)
                    acc[m][n] = __builtin_amdgcn_mfma_f32_16x16x32_bf16(a[m], b[n], acc[m][n], 0, 0, 0);
        }
        __syncthreads();
        cur ^= 1;
    }

    // epilogue: bias + relu, store
    const int orow = row0 + wr * 64 + (lane >> 4) * 4;
    const int ocol = col0 + wc * 64 + lrow;
#pragma unroll
    for (int n = 0; n < 4; ++n) {
        float bv = bias[ocol + n * 16];
#pragma unroll
        for (int m = 0; m < 4; ++m) {
#pragma unroll
            for (int r = 0; r < 4; ++r) {
                float v = fmaxf(acc[m][n][r] + bv, 0.f);
                size_t idx = (size_t)(orow + m * 16 + r) * N + (ocol + n * 16);
                if constexpr (OUT_BF16)
                    ((short*)Cv)[idx] = f2bf(v);
                else
                    ((float*)Cv)[idx] = v;
            }
        }
    }
}

extern "C" void kernel_launch(void* const* d_in, const int* in_sizes, int n_in,
                              void* d_out, int out_size, void* d_ws, size_t ws_size,
                              hipStream_t stream) {
    const float* nodes = (const float*)d_in[0];
    const int*   edges = (const int*)d_in[1];
    const float* W0    = (const float*)d_in[2];
    const float* b0    = (const float*)d_in[3];
    const float* W1    = (const float*)d_in[4];
    const float* b1    = (const float*)d_in[5];
    float* out = (float*)d_out;

    char* ws = (char*)d_ws;
    size_t off = 0;
    auto alloc = [&](size_t bytes) -> char* {
        char* p = ws + off;
        off = (off + bytes + 255) & ~(size_t)255;
        return p;
    };
    int*   cnt    = (int*)alloc((size_t)NB * NN * 4);
    int*   bucket = (int*)alloc((size_t)NB * NN * BCAP * 4);   // 4 MB
    short* W0t    = (short*)alloc((size_t)HID * OBS * 2);
    short* W1t    = (short*)alloc((size_t)OUTF * HID * 2);
    short* z0     = (short*)alloc((size_t)NB * NN * OBS * 2);  // 4 MB
    short* x1     = (short*)alloc((size_t)NB * NN * HID * 2);  // 8 MB
    short* z1     = (short*)alloc((size_t)NB * NN * HID * 2);  // 8 MB

    // 1: weight transposes + zero cnt
    k_prep<<<(HID * OUTF + 255) / 256, 256, 0, stream>>>(W0, W1, W0t, W1t, cnt);
    // 2: bucket scatter (device-wide atomics, 512 blocks)
    k_bucket<<<(NB * NE + 255) / 256, 256, 0, stream>>>(edges, cnt, bucket);

    // 3-4: Layer 1: z0 = S.nodes ; x1 = relu(z0 @ W0 + b0)   [bf16]
    k_agg0<<<dim3(NN / 4, NB), 256, 0, stream>>>(nodes, cnt, bucket, (unsigned*)z0);
    gemm_mfma<OBS, HID, true><<<(NB * NN / 128) * (HID / 128), 256, 0, stream>>>(z0, W0t, b0, x1);

    // 5-6: Layer 2: z1 = S.x1 ; out = relu(z1 @ W1 + b1)     [f32 out]
    k_agg1<<<dim3(NN / 4, NB), 256, 0, stream>>>(x1, cnt, bucket, (unsigned*)z1);
    gemm_mfma<HID, OUTF, false><<<(NB * NN / 128) * (OUTF / 128), 256, 0, stream>>>(z1, W1t, b1, out);
}